// Round 4
// baseline (1445.370 us; speedup 1.0000x reference)
//
#include <hip/hip_runtime.h>
#include <hip/hip_bf16.h>
#include <math.h>

#define NN 10000
#define NE 60000
#define DD 128
#define NL 15
#define LN_EPS 1e-5f

typedef __attribute__((ext_vector_type(8))) short short8;       // 8 bf16 (MFMA A/B frag)
typedef __attribute__((ext_vector_type(4))) float floatx4;      // MFMA C/D frag

__device__ __forceinline__ unsigned short f2bf(float f) {
    unsigned u = __float_as_uint(f);
    u += 0x7fff + ((u >> 16) & 1);   // RNE
    return (unsigned short)(u >> 16);
}
// packed f32x2 -> bf16x2 (v_cvt_pk_bf16_f32 on gfx950), result as one uint
__device__ __forceinline__ unsigned bc2(float a, float b) {
    __hip_bfloat162 t = __float22bfloat162_rn(make_float2(a, b));
    return *(unsigned*)&t;
}
// gelu(y) ~= y * sigmoid(1.5957691*y + 0.0713548*y^3)
__device__ __forceinline__ float gelu_fast(float y) {
    float u = y * y;
    float s2 = y * fmaf(u, 0.07135481283f, 1.59576912161f);
    return y * __builtin_amdgcn_rcpf(1.0f + __expf(-s2));
}

// ---- pack fp32 weights [L][K][N] -> bf16 MFMA B-fragment layout ----
// dst (within layer) = (t*S + s)*512 + l*8 + j ; virtual k = 32s+8(l>>4)+j ; n=16t+(l&15)
// PERM (stage-2 weights, K=256): physical k = ((kv&15)<<4)|(kv>>4)
__device__ __forceinline__ void pack_one(const float* __restrict__ W, unsigned short* __restrict__ P,
                                         int u, int Kk, int Nk, bool perm) {
    int per_layer = Kk * Nk;
    int i = u / per_layer;
    int v0 = u - i * per_layer;
    int S = Kk >> 5;
    int t = v0 / (S * 512);
    int rem = v0 - t * (S * 512);
    int s = rem >> 9;
    int v = rem & 511;
    int l = v >> 3, j = v & 7;
    int kv = (s << 5) + ((l >> 4) << 3) + j;
    int k = perm ? (((kv & 15) << 4) | (kv >> 4)) : kv;
    int n = (t << 4) + (l & 15);
    P[u] = f2bf(W[((size_t)i * Kk + k) * Nk + n]);
}

#define N_EW1 (NL * 384 * 256)
#define N_EW2 (NL * 256 * 128)
#define N_NW1 (NL * 256 * 256)
#define N_NW2 (NL * 256 * 128)

__global__ void pack_all(const float* __restrict__ ew1, const float* __restrict__ ew2,
                         const float* __restrict__ nw1, const float* __restrict__ nw2,
                         unsigned short* __restrict__ P) {
    int tid = blockIdx.x * blockDim.x + threadIdx.x;
    if (tid < N_EW1) { pack_one(ew1, P, tid, 384, 256, false); return; }
    tid -= N_EW1;
    if (tid < N_EW2) { pack_one(ew2, P + N_EW1, tid, 256, 128, true); return; }
    tid -= N_EW2;
    if (tid < N_NW1) { pack_one(nw1, P + N_EW1 + N_EW2, tid, 256, 256, false); return; }
    tid -= N_NW1;
    if (tid < N_NW2) { pack_one(nw2, P + N_EW1 + N_EW2 + N_NW1, tid, 256, 128, true); return; }
}

// ---- CSR build (once per launch) ----
__global__ void hist_kernel(const int* __restrict__ ecol, int* __restrict__ cnt) {
    int e = blockIdx.x * blockDim.x + threadIdx.x;
    if (e < NE) atomicAdd(&cnt[ecol[e]], 1);
}

__global__ void scan_kernel(const int* __restrict__ cnt, int* __restrict__ starts,
                            int* __restrict__ cursor, float* __restrict__ cinv) {
    __shared__ int part[256];
    int t = threadIdx.x;
    const int chunk = (NN + 255) / 256;
    int lo = t * chunk;
    int hi = lo + chunk; if (hi > NN) hi = NN;
    int s = 0;
    for (int n = lo; n < hi; ++n) s += cnt[n];
    part[t] = s;
    __syncthreads();
    for (int off = 1; off < 256; off <<= 1) {
        int v = (t >= off) ? part[t - off] : 0;
        __syncthreads();
        part[t] += v;
        __syncthreads();
    }
    int base = part[t] - s;
    for (int n = lo; n < hi; ++n) {
        int c = cnt[n];
        starts[n] = base; cursor[n] = base;
        cinv[n] = 1.0f / (float)(c > 0 ? c : 1);
        base += c;
    }
}

__global__ void fill_kernel(const int* __restrict__ ecol, int* __restrict__ cursor,
                            int* __restrict__ eidx) {
    int e = blockIdx.x * blockDim.x + threadIdx.x;
    if (e < NE) {
        int slot = atomicAdd(&cursor[ecol[e]], 1);
        eidx[slot] = e;
    }
}

// ---- aggregation: one wave per node, lane covers 2 cols ----
// Reads the bf16 shadow (half the gather bytes of fp32). Output = mean (cinv HERE).
__global__ __launch_bounds__(256)
void agg_kernel(const unsigned short* __restrict__ eab16, const int* __restrict__ starts,
                const int* __restrict__ cnt, const float* __restrict__ cinv,
                const int* __restrict__ eidx, float* __restrict__ agg) {
    int n = blockIdx.x * 4 + (threadIdx.x >> 6);
    if (n >= NN) return;
    int lane = threadIdx.x & 63;
    int st = starts[n], de = cnt[n];
    float sx = 0.f, sy = 0.f;
    for (int i = 0; i < de; ++i) {
        int e = eidx[st + i];
        unsigned v = *(const unsigned*)&eab16[(size_t)e * DD + lane * 2];
        sx += __uint_as_float(v << 16);
        sy += __uint_as_float(v & 0xffff0000u);
    }
    float ci = cinv[n];
    float2 o; o.x = sx * ci; o.y = sy * ci;
    *(float2*)&agg[(size_t)n * DD + lane * 2] = o;
}

// ---- one-time fp32 -> bf16 shadow conversion for x and edge_attr ----
__global__ void init_shadow(const float* __restrict__ x, const float* __restrict__ ea,
                            unsigned short* __restrict__ xb, unsigned short* __restrict__ eb) {
    int t = blockIdx.x * blockDim.x + threadIdx.x;
    const int NX = NN * DD / 4;
    const int NEA = NE * DD / 4;
    if (t < NX) {
        float4 v = *(const float4*)&x[(size_t)t * 4];
        uint2 p; p.x = bc2(v.x, v.y); p.y = bc2(v.z, v.w);
        *(uint2*)&xb[(size_t)t * 4] = p;
    } else if (t < NX + NEA) {
        size_t u = (size_t)(t - NX);
        float4 v = *(const float4*)&ea[u * 4];
        uint2 p; p.x = bc2(v.x, v.y); p.y = bc2(v.z, v.w);
        *(uint2*)&eb[u * 4] = p;
    }
}

// ---- fused MFMA MLP ----
// ROWS rows/block, ROWS/8 waves (edge: 64 rows / 8 waves, amortizes weight-fragment
// loads 2x over rows; node: 32 rows / 4 waves to keep >=313 blocks).
// Gathers read bf16 shadows. Direct scattered epilogue (LDS-staged epilogue measured
// +6.8M bank conflicts / +9us — removed). Aggregation stays a separate CSR pass
// (fused atomics measured 10x worse: 285MB HBM RMW).
//
// Stage-1 wave mapping: qn = w&3 -> n-tiles 4qn..4qn+3 ; pm = w>>2 -> m-tiles 2pm,2pm+1
// Stage-2 wave mapping: np = w&3 -> n-tiles 2np,2np+1 ; mp = w>>2 -> m-tiles 2mp,2mp+1
template <int K1, int ROWS_TOTAL, int ROWS, bool EDGE>
__global__ __launch_bounds__(ROWS * 8, 4)
void mlp_mfma(const unsigned short* __restrict__ xb16,
              const int* __restrict__ erow, const int* __restrict__ ecol,
              const unsigned short* __restrict__ eab16,   // EDGE gather src (own row)
              const float* __restrict__ agg,              // NODE gather src (dense fp32 MEAN)
              float* __restrict__ target,                 // fp32 residual state (ea / x)
              unsigned short* __restrict__ shadow,        // bf16 shadow of target
              const unsigned short* __restrict__ W1p, const unsigned short* __restrict__ W2p,
              const float* __restrict__ b1, const float* __restrict__ g1, const float* __restrict__ bt1,
              const float* __restrict__ b2, const float* __restrict__ g2, const float* __restrict__ bt2)
{
    constexpr int S1 = K1 / 32;
    constexpr int NIT = K1 / 64;      // gather iterations per thread (8 threads/row)
    __shared__ union {
        unsigned short a1[ROWS * K1];     // gather tile (bf16, XOR-swizzled groups of 8)
        unsigned short h[ROWS * 256];     // stage-1 activations, nibble-swapped col layout
    } sm;
    __shared__ float red1[ROWS][8];
    __shared__ float red2[ROWS][8];

    const int tid  = threadIdx.x;
    const int lane = tid & 63;
    const int w    = tid >> 6;
    const int q    = lane >> 4;
    const int c15  = lane & 15;
    const int r0   = blockIdx.x * ROWS;

    const int qn = w & 3;      // stage-1 n-quad
    const int pm = w >> 2;     // stage-1 m-pair (0 when ROWS==32)

    // ---------------- gather -> a1: thread owns row r=tid>>3, col-group g=tid&7 ----------------
    {
        const int r = tid >> 3;
        const int g = tid & 7;
        const int row_g = r0 + r;
        const bool ok = (ROWS_TOTAL % ROWS == 0) || (row_g < ROWS_TOTAL);
        const int rg = ok ? row_g : 0;
        if constexpr (EDGE) {
            const unsigned short* baseA = &xb16[(size_t)erow[rg] * DD];
            const unsigned short* baseB = &xb16[(size_t)ecol[rg] * DD];
            const unsigned short* baseC = &eab16[(size_t)rg * DD];
            #pragma unroll
            for (int it = 0; it < NIT; ++it) {
                const int gg = g + 8 * it;
                const int p = gg << 3;                  // region uniform per it
                const unsigned short* src = (p < 128) ? (baseA + p)
                                          : (p < 256) ? (baseB + (p - 128))
                                                      : (baseC + (p - 256));
                uint4 v = *(const uint4*)src;
                *(uint4*)&sm.a1[r * K1 + ((gg ^ (r & 7)) << 3)] = v;
            }
        } else {
            const unsigned short* baseA = &xb16[(size_t)rg * DD];
            const float* baseB = &agg[(size_t)rg * DD];
            #pragma unroll
            for (int it = 0; it < NIT; ++it) {
                const int gg = g + 8 * it;
                const int p = gg << 3;
                uint4 v;
                if (p < 128) {
                    v = *(const uint4*)(baseA + p);
                } else {
                    float4 f0 = *(const float4*)(baseB + (p - 128));
                    float4 f1 = *(const float4*)(baseB + (p - 124));
                    v.x = bc2(f0.x, f0.y); v.y = bc2(f0.z, f0.w);
                    v.z = bc2(f1.x, f1.y); v.w = bc2(f1.z, f1.w);
                }
                *(uint4*)&sm.a1[r * K1 + ((gg ^ (r & 7)) << 3)] = v;
            }
        }
    }
    __syncthreads();

    // ---------------- stage 1 MFMA ----------------
    floatx4 acc[2][4];
    #pragma unroll
    for (int mt = 0; mt < 2; ++mt)
        #pragma unroll
        for (int ntl = 0; ntl < 4; ++ntl)
            acc[mt][ntl] = (floatx4){0.f, 0.f, 0.f, 0.f};

    #pragma unroll
    for (int s = 0; s < S1; ++s) {
        short8 af[2];
        #pragma unroll
        for (int mt = 0; mt < 2; ++mt) {
            int row  = (((pm << 1) + mt) << 4) + c15;
            int kgrp = ((s << 2) + q) ^ (row & 7);
            af[mt] = *(const short8*)&sm.a1[row * K1 + (kgrp << 3)];
        }
        #pragma unroll
        for (int ntl = 0; ntl < 4; ++ntl) {
            const short8 bf = *(const short8*)&W1p[((((((qn << 2) + ntl) * S1) + s) << 6) + lane) << 3];
            #pragma unroll
            for (int mt = 0; mt < 2; ++mt)
                acc[mt][ntl] = __builtin_amdgcn_mfma_f32_16x16x32_bf16(af[mt], bf, acc[mt][ntl], 0, 0, 0);
        }
    }

    // bias + in-register LN1 partial stats
    float b1c[4], g1c[4], t1c[4];
    #pragma unroll
    for (int ntl = 0; ntl < 4; ++ntl) {
        int col = (((qn << 2) + ntl) << 4) + c15;
        b1c[ntl] = b1[col]; g1c[ntl] = g1[col]; t1c[ntl] = bt1[col];
    }
    #pragma unroll
    for (int mt = 0; mt < 2; ++mt)
        #pragma unroll
        for (int r = 0; r < 4; ++r) {
            float p = 0.f, sq = 0.f;
            #pragma unroll
            for (int ntl = 0; ntl < 4; ++ntl) {
                float v = acc[mt][ntl][r] + b1c[ntl];
                acc[mt][ntl][r] = v;
                p += v; sq += v * v;
            }
            p += __shfl_xor(p, 1);  sq += __shfl_xor(sq, 1);
            p += __shfl_xor(p, 2);  sq += __shfl_xor(sq, 2);
            p += __shfl_xor(p, 4);  sq += __shfl_xor(sq, 4);
            p += __shfl_xor(p, 8);  sq += __shfl_xor(sq, 8);
            if (c15 == 0) {
                int row = (((pm << 1) + mt) << 4) + (q << 2) + r;
                red1[row][(qn << 1) + 0] = p;
                red1[row][(qn << 1) + 1] = sq;
            }
        }
    __syncthreads();   // red1 visible; all waves done with a1 -> h writes safe

    // ---- apply LN1 + GELU in reg, write H' once as b64 (nibble-swapped cols) ----
    #pragma unroll
    for (int mt = 0; mt < 2; ++mt)
        #pragma unroll
        for (int r = 0; r < 4; ++r) {
            int row = (((pm << 1) + mt) << 4) + (q << 2) + r;
            const float4 p0 = *(const float4*)&red1[row][0];
            const float4 p1 = *(const float4*)&red1[row][4];
            float p  = p0.x + p0.z + p1.x + p1.z;
            float sq = p0.y + p0.w + p1.y + p1.w;
            float mu = p * (1.0f / 256.0f);
            float rs = rsqrtf(sq * (1.0f / 256.0f) - mu * mu + LN_EPS);
            float y0 = gelu_fast((acc[mt][0][r] - mu) * rs * g1c[0] + t1c[0]);
            float y1 = gelu_fast((acc[mt][1][r] - mu) * rs * g1c[1] + t1c[1]);
            float y2 = gelu_fast((acc[mt][2][r] - mu) * rs * g1c[2] + t1c[2]);
            float y3 = gelu_fast((acc[mt][3][r] - mu) * rs * g1c[3] + t1c[3]);
            uint2 hp;
            hp.x = bc2(y0, y1);
            hp.y = bc2(y2, y3);
            int gg = (c15 << 1) + (qn >> 1);
            int addr = row * 256 + (((gg ^ (row & 7)) << 3) | ((qn & 1) << 2));
            *(uint2*)&sm.h[addr] = hp;
        }
    __syncthreads();

    // ---------------- stage 2 ----------------
    const int mp = w >> 2;
    const int np = w & 3;
    floatx4 acc2[2][2];
    #pragma unroll
    for (int jm = 0; jm < 2; ++jm)
        #pragma unroll
        for (int jn = 0; jn < 2; ++jn)
            acc2[jm][jn] = (floatx4){0.f, 0.f, 0.f, 0.f};

    #pragma unroll
    for (int s = 0; s < 8; ++s) {
        short8 a2[2];
        #pragma unroll
        for (int jm = 0; jm < 2; ++jm) {
            int mrow = (((mp << 1) + jm) << 4) + c15;
            int kgrp = ((s << 2) + q) ^ (mrow & 7);
            a2[jm] = *(const short8*)&sm.h[mrow * 256 + (kgrp << 3)];
        }
        #pragma unroll
        for (int jn = 0; jn < 2; ++jn) {
            int nt = (np << 1) + jn;
            const short8 b = *(const short8*)&W2p[((((nt << 3) + s) << 6) + lane) << 3];
            #pragma unroll
            for (int jm = 0; jm < 2; ++jm)
                acc2[jm][jn] = __builtin_amdgcn_mfma_f32_16x16x32_bf16(a2[jm], b, acc2[jm][jn], 0, 0, 0);
        }
    }

    float b2c[2], g2c[2], t2c[2];
    #pragma unroll
    for (int jn = 0; jn < 2; ++jn) {
        int col = (((np << 1) + jn) << 4) + c15;
        b2c[jn] = b2[col]; g2c[jn] = g2[col]; t2c[jn] = bt2[col];
    }
    #pragma unroll
    for (int jm = 0; jm < 2; ++jm)
        #pragma unroll
        for (int r = 0; r < 4; ++r) {
            float p = 0.f, sq = 0.f;
            #pragma unroll
            for (int jn = 0; jn < 2; ++jn) {
                float v = acc2[jm][jn][r] + b2c[jn];
                acc2[jm][jn][r] = v;
                p += v; sq += v * v;
            }
            p += __shfl_xor(p, 1);  sq += __shfl_xor(sq, 1);
            p += __shfl_xor(p, 2);  sq += __shfl_xor(sq, 2);
            p += __shfl_xor(p, 4);  sq += __shfl_xor(sq, 4);
            p += __shfl_xor(p, 8);  sq += __shfl_xor(sq, 8);
            if (c15 == 0) {
                int row = (((mp << 1) + jm) << 4) + (q << 2) + r;
                red2[row][(np << 1) + 0] = p;
                red2[row][(np << 1) + 1] = sq;
            }
        }
    __syncthreads();

    // ---------------- epilogue: LN2 + residual += + bf16 shadow (direct scatter) ----------------
    #pragma unroll
    for (int jm = 0; jm < 2; ++jm)
        #pragma unroll
        for (int r = 0; r < 4; ++r) {
            int row = (((mp << 1) + jm) << 4) + (q << 2) + r;
            const float4 pp0 = *(const float4*)&red2[row][0];
            const float4 pp1 = *(const float4*)&red2[row][4];
            float p  = pp0.x + pp0.z + pp1.x + pp1.z;
            float sq = pp0.y + pp0.w + pp1.y + pp1.w;
            float mu = p * (1.0f / 128.0f);
            float rs = rsqrtf(sq * (1.0f / 128.0f) - mu * mu + LN_EPS);
            int rowg = r0 + row;
            if (ROWS_TOTAL % ROWS == 0 || rowg < ROWS_TOTAL) {
                #pragma unroll
                for (int jn = 0; jn < 2; ++jn) {
                    int col = (((np << 1) + jn) << 4) + c15;
                    float o = (acc2[jm][jn][r] - mu) * rs * g2c[jn] + t2c[jn];
                    float t = target[(size_t)rowg * DD + col] + o;
                    target[(size_t)rowg * DD + col] = t;
                    shadow[(size_t)rowg * DD + col] = f2bf(t);
                }
            }
        }
}

extern "C" void kernel_launch(void* const* d_in, const int* in_sizes, int n_in,
                              void* d_out, int out_size, void* d_ws, size_t ws_size,
                              hipStream_t stream) {
    const float* x_in  = (const float*)d_in[0];
    const int*   ei    = (const int*)  d_in[1];
    const float* ea_in = (const float*)d_in[2];
    const float* ew1 = (const float*)d_in[3];
    const float* eb1 = (const float*)d_in[4];
    const float* eg1 = (const float*)d_in[5];
    const float* ebt1= (const float*)d_in[6];
    const float* ew2 = (const float*)d_in[7];
    const float* eb2 = (const float*)d_in[8];
    const float* eg2 = (const float*)d_in[9];
    const float* ebt2= (const float*)d_in[10];
    const float* nw1 = (const float*)d_in[11];
    const float* nb1 = (const float*)d_in[12];
    const float* ng1 = (const float*)d_in[13];
    const float* nbt1= (const float*)d_in[14];
    const float* nw2 = (const float*)d_in[15];
    const float* nb2 = (const float*)d_in[16];
    const float* ng2 = (const float*)d_in[17];
    const float* nbt2= (const float*)d_in[18];

    const int* erow = ei;
    const int* ecol = ei + NE;

    float* xbuf  = (float*)d_out;            // [NN, DD] fp32 residual state
    float* eabuf = (float*)d_out + NN * DD;  // [NE, DD] fp32 residual state

    // workspace layout
    unsigned short* ew1p  = (unsigned short*)d_ws;
    unsigned short* ew2p  = ew1p + N_EW1;
    unsigned short* nw1p  = ew2p + N_EW2;
    unsigned short* nw2p  = nw1p + N_NW1;
    unsigned short* xb16  = nw2p + N_NW2;           // [NN, DD] bf16 shadow of x
    unsigned short* eab16 = xb16 + (size_t)NN * DD; // [NE, DD] bf16 shadow of edge_attr
    int*   cnt    = (int*)(eab16 + (size_t)NE * DD);
    int*   starts = cnt + NN;
    int*   cursor = starts + NN;
    int*   eidx   = cursor + NN;
    float* cinv   = (float*)(eidx + NE);
    float* agg    = cinv + NN;                      // [NN, DD] fp32 (mean)

    hipMemcpyAsync(xbuf,  x_in,  (size_t)NN * DD * sizeof(float), hipMemcpyDeviceToDevice, stream);
    hipMemcpyAsync(eabuf, ea_in, (size_t)NE * DD * sizeof(float), hipMemcpyDeviceToDevice, stream);

    // CSR build
    hipMemsetAsync(cnt, 0, NN * sizeof(int), stream);
    hist_kernel<<<(NE + 255) / 256, 256, 0, stream>>>(ecol, cnt);
    scan_kernel<<<1, 256, 0, stream>>>(cnt, starts, cursor, cinv);
    fill_kernel<<<(NE + 255) / 256, 256, 0, stream>>>(ecol, cursor, eidx);

    // bf16 shadows of the initial state
    {
        int ntot = (NN * DD + NE * DD) / 4;
        init_shadow<<<(ntot + 255) / 256, 256, 0, stream>>>(x_in, ea_in, xb16, eab16);
    }

    // weight packing (stage-2 weights get the k-permutation)
    {
        int ntot = N_EW1 + N_EW2 + N_NW1 + N_NW2;
        pack_all<<<(ntot + 255) / 256, 256, 0, stream>>>(ew1, ew2, nw1, nw2, ew1p);
    }

    for (int i = 0; i < NL; ++i) {
        mlp_mfma<384, NE, 64, true><<<(NE + 63) / 64, 512, 0, stream>>>(
            xb16, erow, ecol, eab16, nullptr, eabuf, eab16,
            ew1p + (size_t)i * 384 * 256, ew2p + (size_t)i * 256 * 128,
            eb1 + (size_t)i * 256, eg1 + (size_t)i * 256, ebt1 + (size_t)i * 256,
            eb2 + (size_t)i * 128, eg2 + (size_t)i * 128, ebt2 + (size_t)i * 128);
        agg_kernel<<<(NN + 3) / 4, 256, 0, stream>>>(eab16, starts, cnt, cinv, eidx, agg);
        mlp_mfma<256, NN, 32, false><<<(NN + 31) / 32, 256, 0, stream>>>(
            xb16, nullptr, nullptr, nullptr, agg, xbuf, xb16,
            nw1p + (size_t)i * 256 * 256, nw2p + (size_t)i * 256 * 128,
            nb1 + (size_t)i * 256, ng1 + (size_t)i * 256, nbt1 + (size_t)i * 256,
            nb2 + (size_t)i * 128, ng2 + (size_t)i * 128, nbt2 + (size_t)i * 128);
    }
}

// Round 5
// 1191.957 us; speedup vs baseline: 1.2126x; 1.2126x over previous
//
#include <hip/hip_runtime.h>
#include <hip/hip_bf16.h>
#include <math.h>

#define NN 10000
#define NE 60000
#define DD 128
#define NL 15
#define LN_EPS 1e-5f

typedef __attribute__((ext_vector_type(8))) short short8;       // 8 bf16 (MFMA A/B frag)
typedef __attribute__((ext_vector_type(4))) float floatx4;      // MFMA C/D frag

__device__ __forceinline__ unsigned short f2bf(float f) {
    unsigned u = __float_as_uint(f);
    u += 0x7fff + ((u >> 16) & 1);   // RNE
    return (unsigned short)(u >> 16);
}
// packed f32x2 -> bf16x2 (v_cvt_pk_bf16_f32 on gfx950), result as one uint
__device__ __forceinline__ unsigned bc2(float a, float b) {
    __hip_bfloat162 t = __float22bfloat162_rn(make_float2(a, b));
    return *(unsigned*)&t;
}
// gelu(y) ~= y * sigmoid(1.5957691*y + 0.0713548*y^3)
__device__ __forceinline__ float gelu_fast(float y) {
    float u = y * y;
    float s2 = y * fmaf(u, 0.07135481283f, 1.59576912161f);
    return y * __builtin_amdgcn_rcpf(1.0f + __expf(-s2));
}

// ---- pack fp32 weights [L][K][N] -> bf16 MFMA B-fragment layout ----
// dst (within layer) = (t*S + s)*512 + l*8 + j ; virtual k = 32s+8(l>>4)+j ; n=16t+(l&15)
// PERM (stage-2 weights, K=256): physical k = ((kv&15)<<4)|(kv>>4)
__device__ __forceinline__ void pack_one(const float* __restrict__ W, unsigned short* __restrict__ P,
                                         int u, int Kk, int Nk, bool perm) {
    int per_layer = Kk * Nk;
    int i = u / per_layer;
    int v0 = u - i * per_layer;
    int S = Kk >> 5;
    int t = v0 / (S * 512);
    int rem = v0 - t * (S * 512);
    int s = rem >> 9;
    int v = rem & 511;
    int l = v >> 3, j = v & 7;
    int kv = (s << 5) + ((l >> 4) << 3) + j;
    int k = perm ? (((kv & 15) << 4) | (kv >> 4)) : kv;
    int n = (t << 4) + (l & 15);
    P[u] = f2bf(W[((size_t)i * Kk + k) * Nk + n]);
}

#define N_EW1 (NL * 384 * 256)
#define N_EW2 (NL * 256 * 128)
#define N_NW1 (NL * 256 * 256)
#define N_NW2 (NL * 256 * 128)

__global__ void pack_all(const float* __restrict__ ew1, const float* __restrict__ ew2,
                         const float* __restrict__ nw1, const float* __restrict__ nw2,
                         unsigned short* __restrict__ P) {
    int tid = blockIdx.x * blockDim.x + threadIdx.x;
    if (tid < N_EW1) { pack_one(ew1, P, tid, 384, 256, false); return; }
    tid -= N_EW1;
    if (tid < N_EW2) { pack_one(ew2, P + N_EW1, tid, 256, 128, true); return; }
    tid -= N_EW2;
    if (tid < N_NW1) { pack_one(nw1, P + N_EW1 + N_EW2, tid, 256, 256, false); return; }
    tid -= N_NW1;
    if (tid < N_NW2) { pack_one(nw2, P + N_EW1 + N_EW2 + N_NW1, tid, 256, 128, true); return; }
}

// ---- CSR build (once per launch) ----
__global__ void hist_kernel(const int* __restrict__ ecol, int* __restrict__ cnt) {
    int e = blockIdx.x * blockDim.x + threadIdx.x;
    if (e < NE) atomicAdd(&cnt[ecol[e]], 1);
}

__global__ void scan_kernel(const int* __restrict__ cnt, int* __restrict__ starts,
                            int* __restrict__ cursor, float* __restrict__ cinv) {
    __shared__ int part[256];
    int t = threadIdx.x;
    const int chunk = (NN + 255) / 256;
    int lo = t * chunk;
    int hi = lo + chunk; if (hi > NN) hi = NN;
    int s = 0;
    for (int n = lo; n < hi; ++n) s += cnt[n];
    part[t] = s;
    __syncthreads();
    for (int off = 1; off < 256; off <<= 1) {
        int v = (t >= off) ? part[t - off] : 0;
        __syncthreads();
        part[t] += v;
        __syncthreads();
    }
    int base = part[t] - s;
    for (int n = lo; n < hi; ++n) {
        int c = cnt[n];
        starts[n] = base; cursor[n] = base;
        cinv[n] = 1.0f / (float)(c > 0 ? c : 1);
        base += c;
    }
}

__global__ void fill_kernel(const int* __restrict__ ecol, int* __restrict__ cursor,
                            int* __restrict__ eidx) {
    int e = blockIdx.x * blockDim.x + threadIdx.x;
    if (e < NE) {
        int slot = atomicAdd(&cursor[ecol[e]], 1);
        eidx[slot] = e;
    }
}

// ---- one-time fp32 -> bf16 shadow conversion for x ----
__global__ void init_shadow(const float* __restrict__ x, unsigned short* __restrict__ xb) {
    int t = blockIdx.x * blockDim.x + threadIdx.x;
    const int NX = NN * DD / 4;
    if (t < NX) {
        float4 v = *(const float4*)&x[(size_t)t * 4];
        uint2 p; p.x = bc2(v.x, v.y); p.y = bc2(v.z, v.w);
        *(uint2*)&xb[(size_t)t * 4] = p;
    }
}

// ---- fused MFMA MLP ----
// EDGE: gather = bf16 x[row], x[col] + fp32 own edge row; epilogue = direct fp32 RMW
//   (no bf16 edge shadow: measured +9us for zero net traffic in r3/r4).
// NODE: gather = bf16 x row + FUSED CSR mean-aggregation over fp32 edge state
//   (replaces the separate agg_kernel: same reads, same per-slice sum order,
//    saves 15 dispatches + agg round-trip); epilogue additionally writes xb16.
// Aggregation via fused atomics measured 10x worse (285MB HBM RMW) — keep CSR.
//
// Stage-1 wave mapping: qn = w&3 -> n-tiles 4qn..4qn+3 ; pm = w>>2 -> m-tiles 2pm,2pm+1
// Stage-2 wave mapping: np = w&3 -> n-tiles 2np,2np+1 ; mp = w>>2 -> m-tiles 2mp,2mp+1
template <int K1, int ROWS_TOTAL, int ROWS, bool EDGE>
__global__ __launch_bounds__(ROWS * 8, 4)
void mlp_mfma(const unsigned short* __restrict__ xb16,
              const int* __restrict__ erow, const int* __restrict__ ecol,
              const float* __restrict__ easrc,            // fp32 edge state (gather / agg source)
              const int* __restrict__ starts, const int* __restrict__ cnt,
              const float* __restrict__ cinv, const int* __restrict__ eidx,   // NODE only
              float* __restrict__ target,                 // fp32 residual state (ea / x)
              unsigned short* __restrict__ shadow,        // NODE: bf16 shadow of x
              const unsigned short* __restrict__ W1p, const unsigned short* __restrict__ W2p,
              const float* __restrict__ b1, const float* __restrict__ g1, const float* __restrict__ bt1,
              const float* __restrict__ b2, const float* __restrict__ g2, const float* __restrict__ bt2)
{
    constexpr int S1 = K1 / 32;
    __shared__ union {
        unsigned short a1[ROWS * K1];     // gather tile (bf16, XOR-swizzled groups of 8)
        unsigned short h[ROWS * 256];     // stage-1 activations, nibble-swapped col layout
    } sm;
    __shared__ float red1[ROWS][8];
    __shared__ float red2[ROWS][8];

    const int tid  = threadIdx.x;
    const int lane = tid & 63;
    const int w    = tid >> 6;
    const int q    = lane >> 4;
    const int c15  = lane & 15;
    const int r0   = blockIdx.x * ROWS;

    const int qn = w & 3;      // stage-1 n-quad
    const int pm = w >> 2;     // stage-1 m-pair (0 when ROWS==32)

    // ---------------- gather -> a1: thread owns row r=tid>>3, col-group g=tid&7 ----------------
    {
        const int r = tid >> 3;
        const int g = tid & 7;
        const int row_g = r0 + r;
        const bool ok = (ROWS_TOTAL % ROWS == 0) || (row_g < ROWS_TOTAL);
        const int rg = ok ? row_g : 0;
        if constexpr (EDGE) {
            const unsigned short* baseA = &xb16[(size_t)erow[rg] * DD];
            const unsigned short* baseB = &xb16[(size_t)ecol[rg] * DD];
            const float* baseC = &easrc[(size_t)rg * DD];
            #pragma unroll
            for (int it = 0; it < 6; ++it) {
                const int gg = g + 8 * it;
                const int p = gg << 3;                  // region uniform per it
                uint4 v;
                if (p < 128) {
                    v = *(const uint4*)(baseA + p);
                } else if (p < 256) {
                    v = *(const uint4*)(baseB + (p - 128));
                } else {
                    float4 f0 = *(const float4*)(baseC + (p - 256));
                    float4 f1 = *(const float4*)(baseC + (p - 252));
                    v.x = bc2(f0.x, f0.y); v.y = bc2(f0.z, f0.w);
                    v.z = bc2(f1.x, f1.y); v.w = bc2(f1.z, f1.w);
                }
                *(uint4*)&sm.a1[r * K1 + ((gg ^ (r & 7)) << 3)] = v;
            }
        } else {
            // cols 0..127: bf16 x row
            const unsigned short* baseA = &xb16[(size_t)rg * DD];
            #pragma unroll
            for (int it = 0; it < 2; ++it) {
                const int gg = g + 8 * it;
                uint4 v = *(const uint4*)(baseA + (gg << 3));
                *(uint4*)&sm.a1[r * K1 + ((gg ^ (r & 7)) << 3)] = v;
            }
            // cols 128..255: fused CSR mean over incoming edges' fp32 state
            const int st = starts[rg];
            const int de = cnt[rg];
            const float ci = cinv[rg];
            float4 sa0 = {0.f,0.f,0.f,0.f}, sa1 = sa0, sb0 = sa0, sb1 = sa0;
            for (int i = 0; i < de; ++i) {
                const int e = eidx[st + i];
                const float* er = &easrc[(size_t)e * DD + (g << 3)];
                float4 a0 = *(const float4*)(er);
                float4 a1 = *(const float4*)(er + 4);
                float4 b0 = *(const float4*)(er + 64);
                float4 b1 = *(const float4*)(er + 68);
                sa0.x += a0.x; sa0.y += a0.y; sa0.z += a0.z; sa0.w += a0.w;
                sa1.x += a1.x; sa1.y += a1.y; sa1.z += a1.z; sa1.w += a1.w;
                sb0.x += b0.x; sb0.y += b0.y; sb0.z += b0.z; sb0.w += b0.w;
                sb1.x += b1.x; sb1.y += b1.y; sb1.z += b1.z; sb1.w += b1.w;
            }
            uint4 v;
            v.x = bc2(sa0.x * ci, sa0.y * ci); v.y = bc2(sa0.z * ci, sa0.w * ci);
            v.z = bc2(sa1.x * ci, sa1.y * ci); v.w = bc2(sa1.z * ci, sa1.w * ci);
            const int gg2 = g + 16;           // agg cols 8g..8g+7 -> virtual cols 128+8g
            *(uint4*)&sm.a1[r * K1 + ((gg2 ^ (r & 7)) << 3)] = v;
            v.x = bc2(sb0.x * ci, sb0.y * ci); v.y = bc2(sb0.z * ci, sb0.w * ci);
            v.z = bc2(sb1.x * ci, sb1.y * ci); v.w = bc2(sb1.z * ci, sb1.w * ci);
            const int gg3 = g + 24;           // agg cols 64+8g.. -> virtual cols 192+8g
            *(uint4*)&sm.a1[r * K1 + ((gg3 ^ (r & 7)) << 3)] = v;
        }
    }
    __syncthreads();

    // ---------------- stage 1 MFMA ----------------
    floatx4 acc[2][4];
    #pragma unroll
    for (int mt = 0; mt < 2; ++mt)
        #pragma unroll
        for (int ntl = 0; ntl < 4; ++ntl)
            acc[mt][ntl] = (floatx4){0.f, 0.f, 0.f, 0.f};

    #pragma unroll
    for (int s = 0; s < S1; ++s) {
        short8 af[2];
        #pragma unroll
        for (int mt = 0; mt < 2; ++mt) {
            int row  = (((pm << 1) + mt) << 4) + c15;
            int kgrp = ((s << 2) + q) ^ (row & 7);
            af[mt] = *(const short8*)&sm.a1[row * K1 + (kgrp << 3)];
        }
        #pragma unroll
        for (int ntl = 0; ntl < 4; ++ntl) {
            const short8 bf = *(const short8*)&W1p[((((((qn << 2) + ntl) * S1) + s) << 6) + lane) << 3];
            #pragma unroll
            for (int mt = 0; mt < 2; ++mt)
                acc[mt][ntl] = __builtin_amdgcn_mfma_f32_16x16x32_bf16(af[mt], bf, acc[mt][ntl], 0, 0, 0);
        }
    }

    // bias + in-register LN1 partial stats
    float b1c[4], g1c[4], t1c[4];
    #pragma unroll
    for (int ntl = 0; ntl < 4; ++ntl) {
        int col = (((qn << 2) + ntl) << 4) + c15;
        b1c[ntl] = b1[col]; g1c[ntl] = g1[col]; t1c[ntl] = bt1[col];
    }
    #pragma unroll
    for (int mt = 0; mt < 2; ++mt)
        #pragma unroll
        for (int r = 0; r < 4; ++r) {
            float p = 0.f, sq = 0.f;
            #pragma unroll
            for (int ntl = 0; ntl < 4; ++ntl) {
                float v = acc[mt][ntl][r] + b1c[ntl];
                acc[mt][ntl][r] = v;
                p += v; sq += v * v;
            }
            p += __shfl_xor(p, 1);  sq += __shfl_xor(sq, 1);
            p += __shfl_xor(p, 2);  sq += __shfl_xor(sq, 2);
            p += __shfl_xor(p, 4);  sq += __shfl_xor(sq, 4);
            p += __shfl_xor(p, 8);  sq += __shfl_xor(sq, 8);
            if (c15 == 0) {
                int row = (((pm << 1) + mt) << 4) + (q << 2) + r;
                red1[row][(qn << 1) + 0] = p;
                red1[row][(qn << 1) + 1] = sq;
            }
        }
    __syncthreads();   // red1 visible; all waves done with a1 -> h writes safe

    // ---- apply LN1 + GELU in reg, write H' once as b64 (nibble-swapped cols) ----
    #pragma unroll
    for (int mt = 0; mt < 2; ++mt)
        #pragma unroll
        for (int r = 0; r < 4; ++r) {
            int row = (((pm << 1) + mt) << 4) + (q << 2) + r;
            const float4 p0 = *(const float4*)&red1[row][0];
            const float4 p1 = *(const float4*)&red1[row][4];
            float p  = p0.x + p0.z + p1.x + p1.z;
            float sq = p0.y + p0.w + p1.y + p1.w;
            float mu = p * (1.0f / 256.0f);
            float rs = rsqrtf(sq * (1.0f / 256.0f) - mu * mu + LN_EPS);
            float y0 = gelu_fast((acc[mt][0][r] - mu) * rs * g1c[0] + t1c[0]);
            float y1 = gelu_fast((acc[mt][1][r] - mu) * rs * g1c[1] + t1c[1]);
            float y2 = gelu_fast((acc[mt][2][r] - mu) * rs * g1c[2] + t1c[2]);
            float y3 = gelu_fast((acc[mt][3][r] - mu) * rs * g1c[3] + t1c[3]);
            uint2 hp;
            hp.x = bc2(y0, y1);
            hp.y = bc2(y2, y3);
            int gg = (c15 << 1) + (qn >> 1);
            int addr = row * 256 + (((gg ^ (row & 7)) << 3) | ((qn & 1) << 2));
            *(uint2*)&sm.h[addr] = hp;
        }
    __syncthreads();

    // ---------------- stage 2 ----------------
    const int mp = w >> 2;
    const int np = w & 3;
    floatx4 acc2[2][2];
    #pragma unroll
    for (int jm = 0; jm < 2; ++jm)
        #pragma unroll
        for (int jn = 0; jn < 2; ++jn)
            acc2[jm][jn] = (floatx4){0.f, 0.f, 0.f, 0.f};

    #pragma unroll
    for (int s = 0; s < 8; ++s) {
        short8 a2[2];
        #pragma unroll
        for (int jm = 0; jm < 2; ++jm) {
            int mrow = (((mp << 1) + jm) << 4) + c15;
            int kgrp = ((s << 2) + q) ^ (mrow & 7);
            a2[jm] = *(const short8*)&sm.h[mrow * 256 + (kgrp << 3)];
        }
        #pragma unroll
        for (int jn = 0; jn < 2; ++jn) {
            int nt = (np << 1) + jn;
            const short8 b = *(const short8*)&W2p[((((nt << 3) + s) << 6) + lane) << 3];
            #pragma unroll
            for (int jm = 0; jm < 2; ++jm)
                acc2[jm][jn] = __builtin_amdgcn_mfma_f32_16x16x32_bf16(a2[jm], b, acc2[jm][jn], 0, 0, 0);
        }
    }

    float b2c[2], g2c[2], t2c[2];
    #pragma unroll
    for (int jn = 0; jn < 2; ++jn) {
        int col = (((np << 1) + jn) << 4) + c15;
        b2c[jn] = b2[col]; g2c[jn] = g2[col]; t2c[jn] = bt2[col];
    }
    #pragma unroll
    for (int jm = 0; jm < 2; ++jm)
        #pragma unroll
        for (int r = 0; r < 4; ++r) {
            float p = 0.f, sq = 0.f;
            #pragma unroll
            for (int jn = 0; jn < 2; ++jn) {
                float v = acc2[jm][jn][r] + b2c[jn];
                acc2[jm][jn][r] = v;
                p += v; sq += v * v;
            }
            p += __shfl_xor(p, 1);  sq += __shfl_xor(sq, 1);
            p += __shfl_xor(p, 2);  sq += __shfl_xor(sq, 2);
            p += __shfl_xor(p, 4);  sq += __shfl_xor(sq, 4);
            p += __shfl_xor(p, 8);  sq += __shfl_xor(sq, 8);
            if (c15 == 0) {
                int row = (((mp << 1) + jm) << 4) + (q << 2) + r;
                red2[row][(np << 1) + 0] = p;
                red2[row][(np << 1) + 1] = sq;
            }
        }
    __syncthreads();

    // ---------------- epilogue: LN2 + residual += (+ xb16 shadow for NODE) ----------------
    #pragma unroll
    for (int jm = 0; jm < 2; ++jm)
        #pragma unroll
        for (int r = 0; r < 4; ++r) {
            int row = (((mp << 1) + jm) << 4) + (q << 2) + r;
            const float4 pp0 = *(const float4*)&red2[row][0];
            const float4 pp1 = *(const float4*)&red2[row][4];
            float p  = pp0.x + pp0.z + pp1.x + pp1.z;
            float sq = pp0.y + pp0.w + pp1.y + pp1.w;
            float mu = p * (1.0f / 128.0f);
            float rs = rsqrtf(sq * (1.0f / 128.0f) - mu * mu + LN_EPS);
            int rowg = r0 + row;
            if (ROWS_TOTAL % ROWS == 0 || rowg < ROWS_TOTAL) {
                #pragma unroll
                for (int jn = 0; jn < 2; ++jn) {
                    int col = (((np << 1) + jn) << 4) + c15;
                    float o = (acc2[jm][jn][r] - mu) * rs * g2c[jn] + t2c[jn];
                    float t = target[(size_t)rowg * DD + col] + o;
                    target[(size_t)rowg * DD + col] = t;
                    if constexpr (!EDGE)
                        shadow[(size_t)rowg * DD + col] = f2bf(t);
                }
            }
        }
}

extern "C" void kernel_launch(void* const* d_in, const int* in_sizes, int n_in,
                              void* d_out, int out_size, void* d_ws, size_t ws_size,
                              hipStream_t stream) {
    const float* x_in  = (const float*)d_in[0];
    const int*   ei    = (const int*)  d_in[1];
    const float* ea_in = (const float*)d_in[2];
    const float* ew1 = (const float*)d_in[3];
    const float* eb1 = (const float*)d_in[4];
    const float* eg1 = (const float*)d_in[5];
    const float* ebt1= (const float*)d_in[6];
    const float* ew2 = (const float*)d_in[7];
    const float* eb2 = (const float*)d_in[8];
    const float* eg2 = (const float*)d_in[9];
    const float* ebt2= (const float*)d_in[10];
    const float* nw1 = (const float*)d_in[11];
    const float* nb1 = (const float*)d_in[12];
    const float* ng1 = (const float*)d_in[13];
    const float* nbt1= (const float*)d_in[14];
    const float* nw2 = (const float*)d_in[15];
    const float* nb2 = (const float*)d_in[16];
    const float* ng2 = (const float*)d_in[17];
    const float* nbt2= (const float*)d_in[18];

    const int* erow = ei;
    const int* ecol = ei + NE;

    float* xbuf  = (float*)d_out;            // [NN, DD] fp32 residual state
    float* eabuf = (float*)d_out + NN * DD;  // [NE, DD] fp32 residual state

    // workspace layout
    unsigned short* ew1p  = (unsigned short*)d_ws;
    unsigned short* ew2p  = ew1p + N_EW1;
    unsigned short* nw1p  = ew2p + N_EW2;
    unsigned short* nw2p  = nw1p + N_NW1;
    unsigned short* xb16  = nw2p + N_NW2;           // [NN, DD] bf16 shadow of x
    int*   cnt    = (int*)(xb16 + (size_t)NN * DD);
    int*   starts = cnt + NN;
    int*   cursor = starts + NN;
    int*   eidx   = cursor + NN;
    float* cinv   = (float*)(eidx + NE);

    hipMemcpyAsync(xbuf,  x_in,  (size_t)NN * DD * sizeof(float), hipMemcpyDeviceToDevice, stream);
    hipMemcpyAsync(eabuf, ea_in, (size_t)NE * DD * sizeof(float), hipMemcpyDeviceToDevice, stream);

    // CSR build
    hipMemsetAsync(cnt, 0, NN * sizeof(int), stream);
    hist_kernel<<<(NE + 255) / 256, 256, 0, stream>>>(ecol, cnt);
    scan_kernel<<<1, 256, 0, stream>>>(cnt, starts, cursor, cinv);
    fill_kernel<<<(NE + 255) / 256, 256, 0, stream>>>(ecol, cursor, eidx);

    // bf16 shadow of initial x
    init_shadow<<<(NN * DD / 4 + 255) / 256, 256, 0, stream>>>(x_in, xb16);

    // weight packing (stage-2 weights get the k-permutation)
    {
        int ntot = N_EW1 + N_EW2 + N_NW1 + N_NW2;
        pack_all<<<(ntot + 255) / 256, 256, 0, stream>>>(ew1, ew2, nw1, nw2, ew1p);
    }

    for (int i = 0; i < NL; ++i) {
        mlp_mfma<384, NE, 32, true><<<NE / 32, 256, 0, stream>>>(
            xb16, erow, ecol, eabuf, nullptr, nullptr, nullptr, nullptr,
            eabuf, nullptr,
            ew1p + (size_t)i * 384 * 256, ew2p + (size_t)i * 256 * 128,
            eb1 + (size_t)i * 256, eg1 + (size_t)i * 256, ebt1 + (size_t)i * 256,
            eb2 + (size_t)i * 128, eg2 + (size_t)i * 128, ebt2 + (size_t)i * 128);
        mlp_mfma<256, NN, 32, false><<<(NN + 31) / 32, 256, 0, stream>>>(
            xb16, nullptr, nullptr, eabuf, starts, cnt, cinv, eidx,
            xbuf, xb16,
            nw1p + (size_t)i * 256 * 256, nw2p + (size_t)i * 256 * 128,
            nb1 + (size_t)i * 256, ng1 + (size_t)i * 256, nbt1 + (size_t)i * 256,
            nb2 + (size_t)i * 128, ng2 + (size_t)i * 128, nbt2 + (size_t)i * 128);
    }
}

// Round 6
// 1178.024 us; speedup vs baseline: 1.2269x; 1.0118x over previous
//
#include <hip/hip_runtime.h>
#include <hip/hip_bf16.h>
#include <math.h>

#define NN 10000
#define NE 60000
#define DD 128
#define NL 15
#define LN_EPS 1e-5f

typedef __attribute__((ext_vector_type(8))) short short8;       // 8 bf16 (MFMA A/B frag)
typedef __attribute__((ext_vector_type(4))) float floatx4;      // MFMA C/D frag

__device__ __forceinline__ unsigned short f2bf(float f) {
    unsigned u = __float_as_uint(f);
    u += 0x7fff + ((u >> 16) & 1);   // RNE
    return (unsigned short)(u >> 16);
}
// packed f32x2 -> bf16x2 (v_cvt_pk_bf16_f32 on gfx950), result as one uint
__device__ __forceinline__ unsigned bc2(float a, float b) {
    __hip_bfloat162 t = __float22bfloat162_rn(make_float2(a, b));
    return *(unsigned*)&t;
}
// gelu(y) ~= y * sigmoid(1.5957691*y + 0.0713548*y^3)
__device__ __forceinline__ float gelu_fast(float y) {
    float u = y * y;
    float s2 = y * fmaf(u, 0.07135481283f, 1.59576912161f);
    return y * __builtin_amdgcn_rcpf(1.0f + __expf(-s2));
}

// ---- pack fp32 weights [L][K][N] -> bf16 MFMA B-fragment layout ----
// dst (within layer) = (t*S + s)*512 + l*8 + j ; virtual k = 32s+8(l>>4)+j ; n=16t+(l&15)
// PERM (stage-2 weights, K=256): physical k = ((kv&15)<<4)|(kv>>4)
__device__ __forceinline__ void pack_one(const float* __restrict__ W, unsigned short* __restrict__ P,
                                         int u, int Kk, int Nk, bool perm) {
    int per_layer = Kk * Nk;
    int i = u / per_layer;
    int v0 = u - i * per_layer;
    int S = Kk >> 5;
    int t = v0 / (S * 512);
    int rem = v0 - t * (S * 512);
    int s = rem >> 9;
    int v = rem & 511;
    int l = v >> 3, j = v & 7;
    int kv = (s << 5) + ((l >> 4) << 3) + j;
    int k = perm ? (((kv & 15) << 4) | (kv >> 4)) : kv;
    int n = (t << 4) + (l & 15);
    P[u] = f2bf(W[((size_t)i * Kk + k) * Nk + n]);
}

#define N_EW1 (NL * 384 * 256)
#define N_EW2 (NL * 256 * 128)
#define N_NW1 (NL * 256 * 256)
#define N_NW2 (NL * 256 * 128)

__global__ void pack_all(const float* __restrict__ ew1, const float* __restrict__ ew2,
                         const float* __restrict__ nw1, const float* __restrict__ nw2,
                         unsigned short* __restrict__ P) {
    int tid = blockIdx.x * blockDim.x + threadIdx.x;
    if (tid < N_EW1) { pack_one(ew1, P, tid, 384, 256, false); return; }
    tid -= N_EW1;
    if (tid < N_EW2) { pack_one(ew2, P + N_EW1, tid, 256, 128, true); return; }
    tid -= N_EW2;
    if (tid < N_NW1) { pack_one(nw1, P + N_EW1 + N_EW2, tid, 256, 256, false); return; }
    tid -= N_NW1;
    if (tid < N_NW2) { pack_one(nw2, P + N_EW1 + N_EW2 + N_NW1, tid, 256, 128, true); return; }
}

// ---- CSR build (once per launch) ----
__global__ void hist_kernel(const int* __restrict__ ecol, int* __restrict__ cnt) {
    int e = blockIdx.x * blockDim.x + threadIdx.x;
    if (e < NE) atomicAdd(&cnt[ecol[e]], 1);
}

__global__ void scan_kernel(const int* __restrict__ cnt, int* __restrict__ starts,
                            int* __restrict__ cursor, float* __restrict__ cinv) {
    __shared__ int part[256];
    int t = threadIdx.x;
    const int chunk = (NN + 255) / 256;
    int lo = t * chunk;
    int hi = lo + chunk; if (hi > NN) hi = NN;
    int s = 0;
    for (int n = lo; n < hi; ++n) s += cnt[n];
    part[t] = s;
    __syncthreads();
    for (int off = 1; off < 256; off <<= 1) {
        int v = (t >= off) ? part[t - off] : 0;
        __syncthreads();
        part[t] += v;
        __syncthreads();
    }
    int base = part[t] - s;
    for (int n = lo; n < hi; ++n) {
        int c = cnt[n];
        starts[n] = base; cursor[n] = base;
        cinv[n] = 1.0f / (float)(c > 0 ? c : 1);
        base += c;
    }
}

__global__ void fill_kernel(const int* __restrict__ ecol, int* __restrict__ cursor,
                            int* __restrict__ eidx) {
    int e = blockIdx.x * blockDim.x + threadIdx.x;
    if (e < NE) {
        int slot = atomicAdd(&cursor[ecol[e]], 1);
        eidx[slot] = e;
    }
}

// ---- one-time fp32 -> bf16 shadow conversion for x ----
__global__ void init_shadow(const float* __restrict__ x, unsigned short* __restrict__ xb) {
    int t = blockIdx.x * blockDim.x + threadIdx.x;
    const int NX = NN * DD / 4;
    if (t < NX) {
        float4 v = *(const float4*)&x[(size_t)t * 4];
        uint2 p; p.x = bc2(v.x, v.y); p.y = bc2(v.z, v.w);
        *(uint2*)&xb[(size_t)t * 4] = p;
    }
}

// ---- fused MFMA MLP ----
// EDGE: gather = bf16 x[row], x[col] + fp32 own edge row; epilogue = direct fp32 RMW
//   (no bf16 edge shadow: measured +9us for zero net traffic in r3/r4).
// NODE: gather = bf16 x row + FUSED CSR mean-aggregation over fp32 edge state;
//   epilogue additionally writes xb16.
// Latency-hiding (r6): stage-2 bias loads hoisted above stage-1 (hide under MFMA);
// residual t_old prefetched after stage-2 MFMA (hides under red2 shuffles+barrier;
// regs reuse dead stage-1 acc so VGPR peak stays <=64 = 8-waves/SIMD cliff);
// s_setprio(1) around MFMA clusters (co-resident blocks at different phases).
// Aggregation via fused atomics measured 10x worse (285MB HBM RMW) — keep CSR.
//
// Stage-1 wave mapping: qn = w&3 -> n-tiles 4qn..4qn+3 ; pm = w>>2 -> m-tiles 2pm,2pm+1
// Stage-2 wave mapping: np = w&3 -> n-tiles 2np,2np+1 ; mp = w>>2 -> m-tiles 2mp,2mp+1
template <int K1, int ROWS_TOTAL, int ROWS, bool EDGE>
__global__ __launch_bounds__(ROWS * 8, 4)
void mlp_mfma(const unsigned short* __restrict__ xb16,
              const int* __restrict__ erow, const int* __restrict__ ecol,
              const float* __restrict__ easrc,            // fp32 edge state (gather / agg source)
              const int* __restrict__ starts, const int* __restrict__ cnt,
              const float* __restrict__ cinv, const int* __restrict__ eidx,   // NODE only
              float* __restrict__ target,                 // fp32 residual state (ea / x)
              unsigned short* __restrict__ shadow,        // NODE: bf16 shadow of x
              const unsigned short* __restrict__ W1p, const unsigned short* __restrict__ W2p,
              const float* __restrict__ b1, const float* __restrict__ g1, const float* __restrict__ bt1,
              const float* __restrict__ b2, const float* __restrict__ g2, const float* __restrict__ bt2)
{
    constexpr int S1 = K1 / 32;
    __shared__ union {
        unsigned short a1[ROWS * K1];     // gather tile (bf16, XOR-swizzled groups of 8)
        unsigned short h[ROWS * 256];     // stage-1 activations, nibble-swapped col layout
    } sm;
    __shared__ float red1[ROWS][8];
    __shared__ float red2[ROWS][8];

    const int tid  = threadIdx.x;
    const int lane = tid & 63;
    const int w    = tid >> 6;
    const int q    = lane >> 4;
    const int c15  = lane & 15;
    const int r0   = blockIdx.x * ROWS;

    const int qn = w & 3;      // stage-1 n-quad
    const int pm = w >> 2;     // stage-1 m-pair (0 when ROWS==32)
    const int mp = w >> 2;     // stage-2 m-pair
    const int np = w & 3;      // stage-2 n-pair

    // ---------------- gather -> a1: thread owns row r=tid>>3, col-group g=tid&7 ----------------
    {
        const int r = tid >> 3;
        const int g = tid & 7;
        const int row_g = r0 + r;
        const bool ok = (ROWS_TOTAL % ROWS == 0) || (row_g < ROWS_TOTAL);
        const int rg = ok ? row_g : 0;
        if constexpr (EDGE) {
            const unsigned short* baseA = &xb16[(size_t)erow[rg] * DD];
            const unsigned short* baseB = &xb16[(size_t)ecol[rg] * DD];
            const float* baseC = &easrc[(size_t)rg * DD];
            #pragma unroll
            for (int it = 0; it < 6; ++it) {
                const int gg = g + 8 * it;
                const int p = gg << 3;                  // region uniform per it
                uint4 v;
                if (p < 128) {
                    v = *(const uint4*)(baseA + p);
                } else if (p < 256) {
                    v = *(const uint4*)(baseB + (p - 128));
                } else {
                    float4 f0 = *(const float4*)(baseC + (p - 256));
                    float4 f1 = *(const float4*)(baseC + (p - 252));
                    v.x = bc2(f0.x, f0.y); v.y = bc2(f0.z, f0.w);
                    v.z = bc2(f1.x, f1.y); v.w = bc2(f1.z, f1.w);
                }
                *(uint4*)&sm.a1[r * K1 + ((gg ^ (r & 7)) << 3)] = v;
            }
        } else {
            // cols 0..127: bf16 x row
            const unsigned short* baseA = &xb16[(size_t)rg * DD];
            #pragma unroll
            for (int it = 0; it < 2; ++it) {
                const int gg = g + 8 * it;
                uint4 v = *(const uint4*)(baseA + (gg << 3));
                *(uint4*)&sm.a1[r * K1 + ((gg ^ (r & 7)) << 3)] = v;
            }
            // cols 128..255: fused CSR mean over incoming edges' fp32 state
            const int st = starts[rg];
            const int de = cnt[rg];
            const float ci = cinv[rg];
            float4 sa0 = {0.f,0.f,0.f,0.f}, sa1 = sa0, sb0 = sa0, sb1 = sa0;
            for (int i = 0; i < de; ++i) {
                const int e = eidx[st + i];
                const float* er = &easrc[(size_t)e * DD + (g << 3)];
                float4 a0 = *(const float4*)(er);
                float4 a1 = *(const float4*)(er + 4);
                float4 b0 = *(const float4*)(er + 64);
                float4 b1 = *(const float4*)(er + 68);
                sa0.x += a0.x; sa0.y += a0.y; sa0.z += a0.z; sa0.w += a0.w;
                sa1.x += a1.x; sa1.y += a1.y; sa1.z += a1.z; sa1.w += a1.w;
                sb0.x += b0.x; sb0.y += b0.y; sb0.z += b0.z; sb0.w += b0.w;
                sb1.x += b1.x; sb1.y += b1.y; sb1.z += b1.z; sb1.w += b1.w;
            }
            uint4 v;
            v.x = bc2(sa0.x * ci, sa0.y * ci); v.y = bc2(sa0.z * ci, sa0.w * ci);
            v.z = bc2(sa1.x * ci, sa1.y * ci); v.w = bc2(sa1.z * ci, sa1.w * ci);
            const int gg2 = g + 16;           // agg cols 8g..8g+7 -> virtual cols 128+8g
            *(uint4*)&sm.a1[r * K1 + ((gg2 ^ (r & 7)) << 3)] = v;
            v.x = bc2(sb0.x * ci, sb0.y * ci); v.y = bc2(sb0.z * ci, sb0.w * ci);
            v.z = bc2(sb1.x * ci, sb1.y * ci); v.w = bc2(sb1.z * ci, sb1.w * ci);
            const int gg3 = g + 24;           // agg cols 64+8g.. -> virtual cols 192+8g
            *(uint4*)&sm.a1[r * K1 + ((gg3 ^ (r & 7)) << 3)] = v;
        }
    }
    __syncthreads();

    // hoisted stage-2 bias/gain loads: latency hides under stage-1 MFMA (6 VGPR)
    float b2c[2], g2c[2], t2c[2];
    #pragma unroll
    for (int jn = 0; jn < 2; ++jn) {
        int col = (((np << 1) + jn) << 4) + c15;
        b2c[jn] = b2[col]; g2c[jn] = g2[col]; t2c[jn] = bt2[col];
    }

    // ---------------- stage 1 MFMA ----------------
    floatx4 acc[2][4];
    #pragma unroll
    for (int mt = 0; mt < 2; ++mt)
        #pragma unroll
        for (int ntl = 0; ntl < 4; ++ntl)
            acc[mt][ntl] = (floatx4){0.f, 0.f, 0.f, 0.f};

    __builtin_amdgcn_s_setprio(1);
    #pragma unroll
    for (int s = 0; s < S1; ++s) {
        short8 af[2];
        #pragma unroll
        for (int mt = 0; mt < 2; ++mt) {
            int row  = (((pm << 1) + mt) << 4) + c15;
            int kgrp = ((s << 2) + q) ^ (row & 7);
            af[mt] = *(const short8*)&sm.a1[row * K1 + (kgrp << 3)];
        }
        #pragma unroll
        for (int ntl = 0; ntl < 4; ++ntl) {
            const short8 bf = *(const short8*)&W1p[((((((qn << 2) + ntl) * S1) + s) << 6) + lane) << 3];
            #pragma unroll
            for (int mt = 0; mt < 2; ++mt)
                acc[mt][ntl] = __builtin_amdgcn_mfma_f32_16x16x32_bf16(af[mt], bf, acc[mt][ntl], 0, 0, 0);
        }
    }
    __builtin_amdgcn_s_setprio(0);

    // bias + in-register LN1 partial stats
    float b1c[4], g1c[4], t1c[4];
    #pragma unroll
    for (int ntl = 0; ntl < 4; ++ntl) {
        int col = (((qn << 2) + ntl) << 4) + c15;
        b1c[ntl] = b1[col]; g1c[ntl] = g1[col]; t1c[ntl] = bt1[col];
    }
    #pragma unroll
    for (int mt = 0; mt < 2; ++mt)
        #pragma unroll
        for (int r = 0; r < 4; ++r) {
            float p = 0.f, sq = 0.f;
            #pragma unroll
            for (int ntl = 0; ntl < 4; ++ntl) {
                float v = acc[mt][ntl][r] + b1c[ntl];
                acc[mt][ntl][r] = v;
                p += v; sq += v * v;
            }
            p += __shfl_xor(p, 1);  sq += __shfl_xor(sq, 1);
            p += __shfl_xor(p, 2);  sq += __shfl_xor(sq, 2);
            p += __shfl_xor(p, 4);  sq += __shfl_xor(sq, 4);
            p += __shfl_xor(p, 8);  sq += __shfl_xor(sq, 8);
            if (c15 == 0) {
                int row = (((pm << 1) + mt) << 4) + (q << 2) + r;
                red1[row][(qn << 1) + 0] = p;
                red1[row][(qn << 1) + 1] = sq;
            }
        }
    __syncthreads();   // red1 visible; all waves done with a1 -> h writes safe

    // ---- apply LN1 + GELU in reg, write H' once as b64 (nibble-swapped cols) ----
    #pragma unroll
    for (int mt = 0; mt < 2; ++mt)
        #pragma unroll
        for (int r = 0; r < 4; ++r) {
            int row = (((pm << 1) + mt) << 4) + (q << 2) + r;
            const float4 p0 = *(const float4*)&red1[row][0];
            const float4 p1 = *(const float4*)&red1[row][4];
            float p  = p0.x + p0.z + p1.x + p1.z;
            float sq = p0.y + p0.w + p1.y + p1.w;
            float mu = p * (1.0f / 256.0f);
            float rs = rsqrtf(sq * (1.0f / 256.0f) - mu * mu + LN_EPS);
            float y0 = gelu_fast((acc[mt][0][r] - mu) * rs * g1c[0] + t1c[0]);
            float y1 = gelu_fast((acc[mt][1][r] - mu) * rs * g1c[1] + t1c[1]);
            float y2 = gelu_fast((acc[mt][2][r] - mu) * rs * g1c[2] + t1c[2]);
            float y3 = gelu_fast((acc[mt][3][r] - mu) * rs * g1c[3] + t1c[3]);
            uint2 hp;
            hp.x = bc2(y0, y1);
            hp.y = bc2(y2, y3);
            int gg = (c15 << 1) + (qn >> 1);
            int addr = row * 256 + (((gg ^ (row & 7)) << 3) | ((qn & 1) << 2));
            *(uint2*)&sm.h[addr] = hp;
        }
    __syncthreads();

    // ---------------- stage 2 ----------------
    floatx4 acc2[2][2];
    #pragma unroll
    for (int jm = 0; jm < 2; ++jm)
        #pragma unroll
        for (int jn = 0; jn < 2; ++jn)
            acc2[jm][jn] = (floatx4){0.f, 0.f, 0.f, 0.f};

    __builtin_amdgcn_s_setprio(1);
    #pragma unroll
    for (int s = 0; s < 8; ++s) {
        short8 a2[2];
        #pragma unroll
        for (int jm = 0; jm < 2; ++jm) {
            int mrow = (((mp << 1) + jm) << 4) + c15;
            int kgrp = ((s << 2) + q) ^ (mrow & 7);
            a2[jm] = *(const short8*)&sm.h[mrow * 256 + (kgrp << 3)];
        }
        #pragma unroll
        for (int jn = 0; jn < 2; ++jn) {
            int nt = (np << 1) + jn;
            const short8 b = *(const short8*)&W2p[((((nt << 3) + s) << 6) + lane) << 3];
            #pragma unroll
            for (int jm = 0; jm < 2; ++jm)
                acc2[jm][jn] = __builtin_amdgcn_mfma_f32_16x16x32_bf16(a2[jm], b, acc2[jm][jn], 0, 0, 0);
        }
    }
    __builtin_amdgcn_s_setprio(0);

    // prefetch residual t_old: 16 scattered loads issued here so their latency hides
    // under the red2 shuffle chain + barrier (regs reuse dead stage-1 acc)
    float tpre[2][4][2];
    #pragma unroll
    for (int jm = 0; jm < 2; ++jm)
        #pragma unroll
        for (int r = 0; r < 4; ++r) {
            int row = (((mp << 1) + jm) << 4) + (q << 2) + r;
            int rowg = r0 + row;
            const bool okk = (ROWS_TOTAL % ROWS == 0) || (rowg < ROWS_TOTAL);
            const int rgs = okk ? rowg : 0;
            #pragma unroll
            for (int jn = 0; jn < 2; ++jn) {
                int col = (((np << 1) + jn) << 4) + c15;
                tpre[jm][r][jn] = target[(size_t)rgs * DD + col];
            }
        }

    #pragma unroll
    for (int jm = 0; jm < 2; ++jm)
        #pragma unroll
        for (int r = 0; r < 4; ++r) {
            float p = 0.f, sq = 0.f;
            #pragma unroll
            for (int jn = 0; jn < 2; ++jn) {
                float v = acc2[jm][jn][r] + b2c[jn];
                acc2[jm][jn][r] = v;
                p += v; sq += v * v;
            }
            p += __shfl_xor(p, 1);  sq += __shfl_xor(sq, 1);
            p += __shfl_xor(p, 2);  sq += __shfl_xor(sq, 2);
            p += __shfl_xor(p, 4);  sq += __shfl_xor(sq, 4);
            p += __shfl_xor(p, 8);  sq += __shfl_xor(sq, 8);
            if (c15 == 0) {
                int row = (((mp << 1) + jm) << 4) + (q << 2) + r;
                red2[row][(np << 1) + 0] = p;
                red2[row][(np << 1) + 1] = sq;
            }
        }
    __syncthreads();

    // ---------------- epilogue: LN2 + residual += (+ xb16 shadow for NODE) ----------------
    #pragma unroll
    for (int jm = 0; jm < 2; ++jm)
        #pragma unroll
        for (int r = 0; r < 4; ++r) {
            int row = (((mp << 1) + jm) << 4) + (q << 2) + r;
            const float4 pp0 = *(const float4*)&red2[row][0];
            const float4 pp1 = *(const float4*)&red2[row][4];
            float p  = pp0.x + pp0.z + pp1.x + pp1.z;
            float sq = pp0.y + pp0.w + pp1.y + pp1.w;
            float mu = p * (1.0f / 128.0f);
            float rs = rsqrtf(sq * (1.0f / 128.0f) - mu * mu + LN_EPS);
            int rowg = r0 + row;
            if (ROWS_TOTAL % ROWS == 0 || rowg < ROWS_TOTAL) {
                #pragma unroll
                for (int jn = 0; jn < 2; ++jn) {
                    int col = (((np << 1) + jn) << 4) + c15;
                    float o = (acc2[jm][jn][r] - mu) * rs * g2c[jn] + t2c[jn];
                    float t = tpre[jm][r][jn] + o;
                    target[(size_t)rowg * DD + col] = t;
                    if constexpr (!EDGE)
                        shadow[(size_t)rowg * DD + col] = f2bf(t);
                }
            }
        }
}

extern "C" void kernel_launch(void* const* d_in, const int* in_sizes, int n_in,
                              void* d_out, int out_size, void* d_ws, size_t ws_size,
                              hipStream_t stream) {
    const float* x_in  = (const float*)d_in[0];
    const int*   ei    = (const int*)  d_in[1];
    const float* ea_in = (const float*)d_in[2];
    const float* ew1 = (const float*)d_in[3];
    const float* eb1 = (const float*)d_in[4];
    const float* eg1 = (const float*)d_in[5];
    const float* ebt1= (const float*)d_in[6];
    const float* ew2 = (const float*)d_in[7];
    const float* eb2 = (const float*)d_in[8];
    const float* eg2 = (const float*)d_in[9];
    const float* ebt2= (const float*)d_in[10];
    const float* nw1 = (const float*)d_in[11];
    const float* nb1 = (const float*)d_in[12];
    const float* ng1 = (const float*)d_in[13];
    const float* nbt1= (const float*)d_in[14];
    const float* nw2 = (const float*)d_in[15];
    const float* nb2 = (const float*)d_in[16];
    const float* ng2 = (const float*)d_in[17];
    const float* nbt2= (const float*)d_in[18];

    const int* erow = ei;
    const int* ecol = ei + NE;

    float* xbuf  = (float*)d_out;            // [NN, DD] fp32 residual state
    float* eabuf = (float*)d_out + NN * DD;  // [NE, DD] fp32 residual state

    // workspace layout
    unsigned short* ew1p  = (unsigned short*)d_ws;
    unsigned short* ew2p  = ew1p + N_EW1;
    unsigned short* nw1p  = ew2p + N_EW2;
    unsigned short* nw2p  = nw1p + N_NW1;
    unsigned short* xb16  = nw2p + N_NW2;           // [NN, DD] bf16 shadow of x
    int*   cnt    = (int*)(xb16 + (size_t)NN * DD);
    int*   starts = cnt + NN;
    int*   cursor = starts + NN;
    int*   eidx   = cursor + NN;
    float* cinv   = (float*)(eidx + NE);

    hipMemcpyAsync(xbuf,  x_in,  (size_t)NN * DD * sizeof(float), hipMemcpyDeviceToDevice, stream);
    hipMemcpyAsync(eabuf, ea_in, (size_t)NE * DD * sizeof(float), hipMemcpyDeviceToDevice, stream);

    // CSR build
    hipMemsetAsync(cnt, 0, NN * sizeof(int), stream);
    hist_kernel<<<(NE + 255) / 256, 256, 0, stream>>>(ecol, cnt);
    scan_kernel<<<1, 256, 0, stream>>>(cnt, starts, cursor, cinv);
    fill_kernel<<<(NE + 255) / 256, 256, 0, stream>>>(ecol, cursor, eidx);

    // bf16 shadow of initial x
    init_shadow<<<(NN * DD / 4 + 255) / 256, 256, 0, stream>>>(x_in, xb16);

    // weight packing (stage-2 weights get the k-permutation)
    {
        int ntot = N_EW1 + N_EW2 + N_NW1 + N_NW2;
        pack_all<<<(ntot + 255) / 256, 256, 0, stream>>>(ew1, ew2, nw1, nw2, ew1p);
    }

    for (int i = 0; i < NL; ++i) {
        mlp_mfma<384, NE, 32, true><<<NE / 32, 256, 0, stream>>>(
            xb16, erow, ecol, eabuf, nullptr, nullptr, nullptr, nullptr,
            eabuf, nullptr,
            ew1p + (size_t)i * 384 * 256, ew2p + (size_t)i * 256 * 128,
            eb1 + (size_t)i * 256, eg1 + (size_t)i * 256, ebt1 + (size_t)i * 256,
            eb2 + (size_t)i * 128, eg2 + (size_t)i * 128, ebt2 + (size_t)i * 128);
        mlp_mfma<256, NN, 32, false><<<(NN + 31) / 32, 256, 0, stream>>>(
            xb16, nullptr, nullptr, eabuf, starts, cnt, cinv, eidx,
            xbuf, xb16,
            nw1p + (size_t)i * 256 * 256, nw2p + (size_t)i * 256 * 128,
            nb1 + (size_t)i * 256, ng1 + (size_t)i * 256, nbt1 + (size_t)i * 256,
            nb2 + (size_t)i * 128, ng2 + (size_t)i * 128, nbt2 + (size_t)i * 128);
    }
}

// Round 7
// 1136.928 us; speedup vs baseline: 1.2713x; 1.0361x over previous
//
#include <hip/hip_runtime.h>
#include <hip/hip_bf16.h>
#include <math.h>

#define NN 10000
#define NE 60000
#define DD 128
#define NL 15
#define LN_EPS 1e-5f

typedef __attribute__((ext_vector_type(8))) short short8;       // 8 bf16 (MFMA A/B frag)
typedef __attribute__((ext_vector_type(4))) float floatx4;      // MFMA C/D frag

__device__ __forceinline__ unsigned short f2bf(float f) {
    unsigned u = __float_as_uint(f);
    u += 0x7fff + ((u >> 16) & 1);   // RNE
    return (unsigned short)(u >> 16);
}
// packed f32x2 -> bf16x2 (v_cvt_pk_bf16_f32 on gfx950), result as one uint
__device__ __forceinline__ unsigned bc2(float a, float b) {
    __hip_bfloat162 t = __float22bfloat162_rn(make_float2(a, b));
    return *(unsigned*)&t;
}
// bf16x2 word -> two floats
__device__ __forceinline__ float bfl(unsigned w) { return __uint_as_float(w << 16); }
__device__ __forceinline__ float bfh(unsigned w) { return __uint_as_float(w & 0xffff0000u); }
// gelu(y) ~= y * sigmoid(1.5957691*y + 0.0713548*y^3)
__device__ __forceinline__ float gelu_fast(float y) {
    float u = y * y;
    float s2 = y * fmaf(u, 0.07135481283f, 1.59576912161f);
    return y * __builtin_amdgcn_rcpf(1.0f + __expf(-s2));
}

// ---- pack fp32 weights [L][K][N] -> bf16 MFMA B-fragment layout ----
// dst (within layer) = (t*S + s)*512 + l*8 + j ; virtual k = 32s+8(l>>4)+j ; n=16t+(l&15)
// PERM (stage-2 weights, K=256): physical k = ((kv&15)<<4)|(kv>>4)
__device__ __forceinline__ void pack_one(const float* __restrict__ W, unsigned short* __restrict__ P,
                                         int u, int Kk, int Nk, bool perm) {
    int per_layer = Kk * Nk;
    int i = u / per_layer;
    int v0 = u - i * per_layer;
    int S = Kk >> 5;
    int t = v0 / (S * 512);
    int rem = v0 - t * (S * 512);
    int s = rem >> 9;
    int v = rem & 511;
    int l = v >> 3, j = v & 7;
    int kv = (s << 5) + ((l >> 4) << 3) + j;
    int k = perm ? (((kv & 15) << 4) | (kv >> 4)) : kv;
    int n = (t << 4) + (l & 15);
    P[u] = f2bf(W[((size_t)i * Kk + k) * Nk + n]);
}

#define N_EW1 (NL * 384 * 256)
#define N_EW2 (NL * 256 * 128)
#define N_NW1 (NL * 256 * 256)
#define N_NW2 (NL * 256 * 128)

__global__ void pack_all(const float* __restrict__ ew1, const float* __restrict__ ew2,
                         const float* __restrict__ nw1, const float* __restrict__ nw2,
                         unsigned short* __restrict__ P) {
    int tid = blockIdx.x * blockDim.x + threadIdx.x;
    if (tid < N_EW1) { pack_one(ew1, P, tid, 384, 256, false); return; }
    tid -= N_EW1;
    if (tid < N_EW2) { pack_one(ew2, P + N_EW1, tid, 256, 128, true); return; }
    tid -= N_EW2;
    if (tid < N_NW1) { pack_one(nw1, P + N_EW1 + N_EW2, tid, 256, 256, false); return; }
    tid -= N_NW1;
    if (tid < N_NW2) { pack_one(nw2, P + N_EW1 + N_EW2 + N_NW1, tid, 256, 128, true); return; }
}

// ---- CSR build (once per launch) ----
__global__ void hist_kernel(const int* __restrict__ ecol, int* __restrict__ cnt) {
    int e = blockIdx.x * blockDim.x + threadIdx.x;
    if (e < NE) atomicAdd(&cnt[ecol[e]], 1);
}

__global__ void scan_kernel(const int* __restrict__ cnt, int* __restrict__ starts,
                            int* __restrict__ cursor, float* __restrict__ cinv) {
    __shared__ int part[256];
    int t = threadIdx.x;
    const int chunk = (NN + 255) / 256;
    int lo = t * chunk;
    int hi = lo + chunk; if (hi > NN) hi = NN;
    int s = 0;
    for (int n = lo; n < hi; ++n) s += cnt[n];
    part[t] = s;
    __syncthreads();
    for (int off = 1; off < 256; off <<= 1) {
        int v = (t >= off) ? part[t - off] : 0;
        __syncthreads();
        part[t] += v;
        __syncthreads();
    }
    int base = part[t] - s;
    for (int n = lo; n < hi; ++n) {
        int c = cnt[n];
        starts[n] = base; cursor[n] = base;
        cinv[n] = 1.0f / (float)(c > 0 ? c : 1);
        base += c;
    }
}

__global__ void fill_kernel(const int* __restrict__ ecol, int* __restrict__ cursor,
                            int* __restrict__ eidx) {
    int e = blockIdx.x * blockDim.x + threadIdx.x;
    if (e < NE) {
        int slot = atomicAdd(&cursor[ecol[e]], 1);
        eidx[slot] = e;
    }
}

// ---- one-time fp32 -> bf16 conversion: x shadow + edge state ----
__global__ void init_shadow(const float* __restrict__ x, const float* __restrict__ ea,
                            unsigned short* __restrict__ xb, unsigned short* __restrict__ eb) {
    int t = blockIdx.x * blockDim.x + threadIdx.x;
    const int NX = NN * DD / 4;
    const int NEA = NE * DD / 4;
    if (t < NX) {
        float4 v = *(const float4*)&x[(size_t)t * 4];
        uint2 p; p.x = bc2(v.x, v.y); p.y = bc2(v.z, v.w);
        *(uint2*)&xb[(size_t)t * 4] = p;
    } else if (t < NX + NEA) {
        size_t u = (size_t)(t - NX);
        float4 v = *(const float4*)&ea[u * 4];
        uint2 p; p.x = bc2(v.x, v.y); p.y = bc2(v.z, v.w);
        *(uint2*)&eb[u * 4] = p;
    }
}

// ---- fused MFMA MLP ----
// Edge state is bf16-ONLY (eas16): gather = 6 uniform uint4 copies (zero convert VALU);
// residual t_old read back from the staged gather tile in LDS (a1 virtual cols 256..383,
// read after stage-1 MFMA / before sm.h overwrite) — no epilogue global RMW read at all.
// Final edge layer additionally writes fp32 to d_out (target != nullptr).
// NODE: gather = bf16 x row + FUSED CSR mean-aggregation over bf16 edge state;
// x residual stays fp32 (xbuf) + bf16 shadow. Fused-atomic agg measured 10x worse — keep CSR.
// r3/r4 lesson: fp32+bf16-shadow DOUBLE state for edges was +9us of pure overhead; this
// round removes the fp32 half instead (round-4 measured bf16-agg absmax 0.1289, thr 0.3975).
//
// Stage-1 wave mapping: qn = w&3 -> n-tiles 4qn..4qn+3 ; pm = w>>2 -> m-tiles 2pm,2pm+1
// Stage-2 wave mapping: np = w&3 -> n-tiles 2np,2np+1 ; mp = w>>2 -> m-tiles 2mp,2mp+1
template <int K1, int ROWS_TOTAL, int ROWS, bool EDGE>
__global__ __launch_bounds__(ROWS * 8, 4)
void mlp_mfma(const unsigned short* __restrict__ xb16,
              const int* __restrict__ erow, const int* __restrict__ ecol,
              const unsigned short* __restrict__ eas16,   // bf16 edge state
              const int* __restrict__ starts, const int* __restrict__ cnt,
              const float* __restrict__ cinv, const int* __restrict__ eidx,   // NODE only
              float* __restrict__ target,                 // NODE: fp32 x state; EDGE: final f32 out or null
              unsigned short* __restrict__ shadow,        // NODE: xb16 ; EDGE: eas16
              const unsigned short* __restrict__ W1p, const unsigned short* __restrict__ W2p,
              const float* __restrict__ b1, const float* __restrict__ g1, const float* __restrict__ bt1,
              const float* __restrict__ b2, const float* __restrict__ g2, const float* __restrict__ bt2)
{
    constexpr int S1 = K1 / 32;
    __shared__ union {
        unsigned short a1[ROWS * K1];     // gather tile (bf16, XOR-swizzled groups of 8)
        unsigned short h[ROWS * 256];     // stage-1 activations, nibble-swapped col layout
    } sm;
    __shared__ float red1[ROWS][8];
    __shared__ float red2[ROWS][8];

    const int tid  = threadIdx.x;
    const int lane = tid & 63;
    const int w    = tid >> 6;
    const int q    = lane >> 4;
    const int c15  = lane & 15;
    const int r0   = blockIdx.x * ROWS;

    const int qn = w & 3;      // stage-1 n-quad
    const int pm = w >> 2;     // stage-1 m-pair (0 when ROWS==32)
    const int mp = w >> 2;     // stage-2 m-pair
    const int np = w & 3;      // stage-2 n-pair

    // ---------------- gather -> a1: thread owns row r=tid>>3, col-group g=tid&7 ----------------
    {
        const int r = tid >> 3;
        const int g = tid & 7;
        const int row_g = r0 + r;
        const bool ok = (ROWS_TOTAL % ROWS == 0) || (row_g < ROWS_TOTAL);
        const int rg = ok ? row_g : 0;
        if constexpr (EDGE) {
            const unsigned short* baseA = &xb16[(size_t)erow[rg] * DD];
            const unsigned short* baseB = &xb16[(size_t)ecol[rg] * DD];
            const unsigned short* baseC = &eas16[(size_t)rg * DD];
            #pragma unroll
            for (int it = 0; it < 6; ++it) {
                const int gg = g + 8 * it;
                const int p = gg << 3;                  // region uniform per it
                const unsigned short* src = (p < 128) ? (baseA + p)
                                          : (p < 256) ? (baseB + (p - 128))
                                                      : (baseC + (p - 256));
                uint4 v = *(const uint4*)src;
                *(uint4*)&sm.a1[r * K1 + ((gg ^ (r & 7)) << 3)] = v;
            }
        } else {
            // cols 0..127: bf16 x row
            const unsigned short* baseA = &xb16[(size_t)rg * DD];
            #pragma unroll
            for (int it = 0; it < 2; ++it) {
                const int gg = g + 8 * it;
                uint4 v = *(const uint4*)(baseA + (gg << 3));
                *(uint4*)&sm.a1[r * K1 + ((gg ^ (r & 7)) << 3)] = v;
            }
            // cols 128..255: fused CSR mean over incoming edges' bf16 state
            const int st = starts[rg];
            const int de = cnt[rg];
            const float ci = cinv[rg];
            float4 sa0 = {0.f,0.f,0.f,0.f}, sa1 = sa0, sb0 = sa0, sb1 = sa0;
            for (int i = 0; i < de; ++i) {
                const int e = eidx[st + i];
                const unsigned short* er = &eas16[(size_t)e * DD + (g << 3)];
                uint4 a = *(const uint4*)er;          // cols 8g..8g+7
                uint4 b = *(const uint4*)(er + 64);   // cols 64+8g..64+8g+7
                sa0.x += bfl(a.x); sa0.y += bfh(a.x); sa0.z += bfl(a.y); sa0.w += bfh(a.y);
                sa1.x += bfl(a.z); sa1.y += bfh(a.z); sa1.z += bfl(a.w); sa1.w += bfh(a.w);
                sb0.x += bfl(b.x); sb0.y += bfh(b.x); sb0.z += bfl(b.y); sb0.w += bfh(b.y);
                sb1.x += bfl(b.z); sb1.y += bfh(b.z); sb1.z += bfl(b.w); sb1.w += bfh(b.w);
            }
            uint4 v;
            v.x = bc2(sa0.x * ci, sa0.y * ci); v.y = bc2(sa0.z * ci, sa0.w * ci);
            v.z = bc2(sa1.x * ci, sa1.y * ci); v.w = bc2(sa1.z * ci, sa1.w * ci);
            const int gg2 = g + 16;           // agg cols 8g..8g+7 -> virtual cols 128+8g
            *(uint4*)&sm.a1[r * K1 + ((gg2 ^ (r & 7)) << 3)] = v;
            v.x = bc2(sb0.x * ci, sb0.y * ci); v.y = bc2(sb0.z * ci, sb0.w * ci);
            v.z = bc2(sb1.x * ci, sb1.y * ci); v.w = bc2(sb1.z * ci, sb1.w * ci);
            const int gg3 = g + 24;           // agg cols 64+8g.. -> virtual cols 192+8g
            *(uint4*)&sm.a1[r * K1 + ((gg3 ^ (r & 7)) << 3)] = v;
        }
    }
    __syncthreads();

    // hoisted stage-2 bias/gain loads: latency hides under stage-1 MFMA (6 VGPR)
    float b2c[2], g2c[2], t2c[2];
    #pragma unroll
    for (int jn = 0; jn < 2; ++jn) {
        int col = (((np << 1) + jn) << 4) + c15;
        b2c[jn] = b2[col]; g2c[jn] = g2[col]; t2c[jn] = bt2[col];
    }

    // ---------------- stage 1 MFMA ----------------
    floatx4 acc[2][4];
    #pragma unroll
    for (int mt = 0; mt < 2; ++mt)
        #pragma unroll
        for (int ntl = 0; ntl < 4; ++ntl)
            acc[mt][ntl] = (floatx4){0.f, 0.f, 0.f, 0.f};

    __builtin_amdgcn_s_setprio(1);
    #pragma unroll
    for (int s = 0; s < S1; ++s) {
        short8 af[2];
        #pragma unroll
        for (int mt = 0; mt < 2; ++mt) {
            int row  = (((pm << 1) + mt) << 4) + c15;
            int kgrp = ((s << 2) + q) ^ (row & 7);
            af[mt] = *(const short8*)&sm.a1[row * K1 + (kgrp << 3)];
        }
        #pragma unroll
        for (int ntl = 0; ntl < 4; ++ntl) {
            const short8 bf = *(const short8*)&W1p[((((((qn << 2) + ntl) * S1) + s) << 6) + lane) << 3];
            #pragma unroll
            for (int mt = 0; mt < 2; ++mt)
                acc[mt][ntl] = __builtin_amdgcn_mfma_f32_16x16x32_bf16(af[mt], bf, acc[mt][ntl], 0, 0, 0);
        }
    }
    __builtin_amdgcn_s_setprio(0);

    // EDGE residual t_old: read own-row bf16 state back from the gather tile in LDS
    // (virtual cols 256..383; a1 is intact until sm.h writes after the next barrier)
    float tpre[2][4][2];
    if constexpr (EDGE) {
        #pragma unroll
        for (int jm = 0; jm < 2; ++jm)
            #pragma unroll
            for (int r = 0; r < 4; ++r) {
                int row = (((mp << 1) + jm) << 4) + (q << 2) + r;
                #pragma unroll
                for (int jn = 0; jn < 2; ++jn) {
                    int col = (((np << 1) + jn) << 4) + c15;
                    int vc = 256 + col;
                    int addr = row * K1 + ((((vc >> 3) ^ (row & 7)) << 3) | (vc & 7));
                    tpre[jm][r][jn] = __uint_as_float((unsigned)sm.a1[addr] << 16);
                }
            }
    }

    // bias + in-register LN1 partial stats
    float b1c[4], g1c[4], t1c[4];
    #pragma unroll
    for (int ntl = 0; ntl < 4; ++ntl) {
        int col = (((qn << 2) + ntl) << 4) + c15;
        b1c[ntl] = b1[col]; g1c[ntl] = g1[col]; t1c[ntl] = bt1[col];
    }
    #pragma unroll
    for (int mt = 0; mt < 2; ++mt)
        #pragma unroll
        for (int r = 0; r < 4; ++r) {
            float p = 0.f, sq = 0.f;
            #pragma unroll
            for (int ntl = 0; ntl < 4; ++ntl) {
                float v = acc[mt][ntl][r] + b1c[ntl];
                acc[mt][ntl][r] = v;
                p += v; sq += v * v;
            }
            p += __shfl_xor(p, 1);  sq += __shfl_xor(sq, 1);
            p += __shfl_xor(p, 2);  sq += __shfl_xor(sq, 2);
            p += __shfl_xor(p, 4);  sq += __shfl_xor(sq, 4);
            p += __shfl_xor(p, 8);  sq += __shfl_xor(sq, 8);
            if (c15 == 0) {
                int row = (((pm << 1) + mt) << 4) + (q << 2) + r;
                red1[row][(qn << 1) + 0] = p;
                red1[row][(qn << 1) + 1] = sq;
            }
        }
    __syncthreads();   // red1 visible; all waves done with a1 (incl. t_old reads) -> h writes safe

    // ---- apply LN1 + GELU in reg, write H' once as b64 (nibble-swapped cols) ----
    #pragma unroll
    for (int mt = 0; mt < 2; ++mt)
        #pragma unroll
        for (int r = 0; r < 4; ++r) {
            int row = (((pm << 1) + mt) << 4) + (q << 2) + r;
            const float4 p0 = *(const float4*)&red1[row][0];
            const float4 p1 = *(const float4*)&red1[row][4];
            float p  = p0.x + p0.z + p1.x + p1.z;
            float sq = p0.y + p0.w + p1.y + p1.w;
            float mu = p * (1.0f / 256.0f);
            float rs = rsqrtf(sq * (1.0f / 256.0f) - mu * mu + LN_EPS);
            float y0 = gelu_fast((acc[mt][0][r] - mu) * rs * g1c[0] + t1c[0]);
            float y1 = gelu_fast((acc[mt][1][r] - mu) * rs * g1c[1] + t1c[1]);
            float y2 = gelu_fast((acc[mt][2][r] - mu) * rs * g1c[2] + t1c[2]);
            float y3 = gelu_fast((acc[mt][3][r] - mu) * rs * g1c[3] + t1c[3]);
            uint2 hp;
            hp.x = bc2(y0, y1);
            hp.y = bc2(y2, y3);
            int gg = (c15 << 1) + (qn >> 1);
            int addr = row * 256 + (((gg ^ (row & 7)) << 3) | ((qn & 1) << 2));
            *(uint2*)&sm.h[addr] = hp;
        }
    __syncthreads();

    // ---------------- stage 2 ----------------
    floatx4 acc2[2][2];
    #pragma unroll
    for (int jm = 0; jm < 2; ++jm)
        #pragma unroll
        for (int jn = 0; jn < 2; ++jn)
            acc2[jm][jn] = (floatx4){0.f, 0.f, 0.f, 0.f};

    __builtin_amdgcn_s_setprio(1);
    #pragma unroll
    for (int s = 0; s < 8; ++s) {
        short8 a2[2];
        #pragma unroll
        for (int jm = 0; jm < 2; ++jm) {
            int mrow = (((mp << 1) + jm) << 4) + c15;
            int kgrp = ((s << 2) + q) ^ (mrow & 7);
            a2[jm] = *(const short8*)&sm.h[mrow * 256 + (kgrp << 3)];
        }
        #pragma unroll
        for (int jn = 0; jn < 2; ++jn) {
            int nt = (np << 1) + jn;
            const short8 b = *(const short8*)&W2p[((((nt << 3) + s) << 6) + lane) << 3];
            #pragma unroll
            for (int jm = 0; jm < 2; ++jm)
                acc2[jm][jn] = __builtin_amdgcn_mfma_f32_16x16x32_bf16(a2[jm], b, acc2[jm][jn], 0, 0, 0);
        }
    }
    __builtin_amdgcn_s_setprio(0);

    // NODE residual t_old: prefetch fp32 x state; latency hides under red2 shuffles+barrier
    if constexpr (!EDGE) {
        #pragma unroll
        for (int jm = 0; jm < 2; ++jm)
            #pragma unroll
            for (int r = 0; r < 4; ++r) {
                int row = (((mp << 1) + jm) << 4) + (q << 2) + r;
                int rowg = r0 + row;
                const bool okk = (ROWS_TOTAL % ROWS == 0) || (rowg < ROWS_TOTAL);
                const int rgs = okk ? rowg : 0;
                #pragma unroll
                for (int jn = 0; jn < 2; ++jn) {
                    int col = (((np << 1) + jn) << 4) + c15;
                    tpre[jm][r][jn] = target[(size_t)rgs * DD + col];
                }
            }
    }

    #pragma unroll
    for (int jm = 0; jm < 2; ++jm)
        #pragma unroll
        for (int r = 0; r < 4; ++r) {
            float p = 0.f, sq = 0.f;
            #pragma unroll
            for (int jn = 0; jn < 2; ++jn) {
                float v = acc2[jm][jn][r] + b2c[jn];
                acc2[jm][jn][r] = v;
                p += v; sq += v * v;
            }
            p += __shfl_xor(p, 1);  sq += __shfl_xor(sq, 1);
            p += __shfl_xor(p, 2);  sq += __shfl_xor(sq, 2);
            p += __shfl_xor(p, 4);  sq += __shfl_xor(sq, 4);
            p += __shfl_xor(p, 8);  sq += __shfl_xor(sq, 8);
            if (c15 == 0) {
                int row = (((mp << 1) + jm) << 4) + (q << 2) + r;
                red2[row][(np << 1) + 0] = p;
                red2[row][(np << 1) + 1] = sq;
            }
        }
    __syncthreads();

    // ---------------- epilogue: LN2 + residual += (bf16 state; NODE also fp32) ----------------
    #pragma unroll
    for (int jm = 0; jm < 2; ++jm)
        #pragma unroll
        for (int r = 0; r < 4; ++r) {
            int row = (((mp << 1) + jm) << 4) + (q << 2) + r;
            const float4 pp0 = *(const float4*)&red2[row][0];
            const float4 pp1 = *(const float4*)&red2[row][4];
            float p  = pp0.x + pp0.z + pp1.x + pp1.z;
            float sq = pp0.y + pp0.w + pp1.y + pp1.w;
            float mu = p * (1.0f / 128.0f);
            float rs = rsqrtf(sq * (1.0f / 128.0f) - mu * mu + LN_EPS);
            int rowg = r0 + row;
            if (ROWS_TOTAL % ROWS == 0 || rowg < ROWS_TOTAL) {
                #pragma unroll
                for (int jn = 0; jn < 2; ++jn) {
                    int col = (((np << 1) + jn) << 4) + c15;
                    float o = (acc2[jm][jn][r] - mu) * rs * g2c[jn] + t2c[jn];
                    float t = tpre[jm][r][jn] + o;
                    shadow[(size_t)rowg * DD + col] = f2bf(t);
                    if constexpr (EDGE) {
                        if (target) target[(size_t)rowg * DD + col] = t;   // final layer only
                    } else {
                        target[(size_t)rowg * DD + col] = t;
                    }
                }
            }
        }
}

extern "C" void kernel_launch(void* const* d_in, const int* in_sizes, int n_in,
                              void* d_out, int out_size, void* d_ws, size_t ws_size,
                              hipStream_t stream) {
    const float* x_in  = (const float*)d_in[0];
    const int*   ei    = (const int*)  d_in[1];
    const float* ea_in = (const float*)d_in[2];
    const float* ew1 = (const float*)d_in[3];
    const float* eb1 = (const float*)d_in[4];
    const float* eg1 = (const float*)d_in[5];
    const float* ebt1= (const float*)d_in[6];
    const float* ew2 = (const float*)d_in[7];
    const float* eb2 = (const float*)d_in[8];
    const float* eg2 = (const float*)d_in[9];
    const float* ebt2= (const float*)d_in[10];
    const float* nw1 = (const float*)d_in[11];
    const float* nb1 = (const float*)d_in[12];
    const float* ng1 = (const float*)d_in[13];
    const float* nbt1= (const float*)d_in[14];
    const float* nw2 = (const float*)d_in[15];
    const float* nb2 = (const float*)d_in[16];
    const float* ng2 = (const float*)d_in[17];
    const float* nbt2= (const float*)d_in[18];

    const int* erow = ei;
    const int* ecol = ei + NE;

    float* xbuf  = (float*)d_out;            // [NN, DD] fp32 x residual state (output 0)
    float* eabuf = (float*)d_out + NN * DD;  // [NE, DD] fp32 edge output (written on last layer)

    // workspace layout
    unsigned short* ew1p  = (unsigned short*)d_ws;
    unsigned short* ew2p  = ew1p + N_EW1;
    unsigned short* nw1p  = ew2p + N_EW2;
    unsigned short* nw2p  = nw1p + N_NW1;
    unsigned short* xb16  = nw2p + N_NW2;            // [NN, DD] bf16 shadow of x
    unsigned short* eas16 = xb16 + (size_t)NN * DD;  // [NE, DD] bf16 edge STATE
    int*   cnt    = (int*)(eas16 + (size_t)NE * DD);
    int*   starts = cnt + NN;
    int*   cursor = starts + NN;
    int*   eidx   = cursor + NN;
    float* cinv   = (float*)(eidx + NE);

    hipMemcpyAsync(xbuf, x_in, (size_t)NN * DD * sizeof(float), hipMemcpyDeviceToDevice, stream);

    // CSR build
    hipMemsetAsync(cnt, 0, NN * sizeof(int), stream);
    hist_kernel<<<(NE + 255) / 256, 256, 0, stream>>>(ecol, cnt);
    scan_kernel<<<1, 256, 0, stream>>>(cnt, starts, cursor, cinv);
    fill_kernel<<<(NE + 255) / 256, 256, 0, stream>>>(ecol, cursor, eidx);

    // bf16 x shadow + bf16 edge state init
    {
        int ntot = (NN * DD + NE * DD) / 4;
        init_shadow<<<(ntot + 255) / 256, 256, 0, stream>>>(x_in, ea_in, xb16, eas16);
    }

    // weight packing (stage-2 weights get the k-permutation)
    {
        int ntot = N_EW1 + N_EW2 + N_NW1 + N_NW2;
        pack_all<<<(ntot + 255) / 256, 256, 0, stream>>>(ew1, ew2, nw1, nw2, ew1p);
    }

    for (int i = 0; i < NL; ++i) {
        mlp_mfma<384, NE, 32, true><<<NE / 32, 256, 0, stream>>>(
            xb16, erow, ecol, eas16, nullptr, nullptr, nullptr, nullptr,
            (i == NL - 1) ? eabuf : nullptr, eas16,
            ew1p + (size_t)i * 384 * 256, ew2p + (size_t)i * 256 * 128,
            eb1 + (size_t)i * 256, eg1 + (size_t)i * 256, ebt1 + (size_t)i * 256,
            eb2 + (size_t)i * 128, eg2 + (size_t)i * 128, ebt2 + (size_t)i * 128);
        mlp_mfma<256, NN, 32, false><<<(NN + 31) / 32, 256, 0, stream>>>(
            xb16, nullptr, nullptr, eas16, starts, cnt, cinv, eidx,
            xbuf, xb16,
            nw1p + (size_t)i * 256 * 256, nw2p + (size_t)i * 256 * 128,
            nb1 + (size_t)i * 256, ng1 + (size_t)i * 256, nbt1 + (size_t)i * 256,
            nb2 + (size_t)i * 128, ng2 + (size_t)i * 128, nbt2 + (size_t)i * 128);
    }
}